// Round 2
// baseline (17.480 us; speedup 1.0000x reference)
//
#include <hip/hip_runtime.h>

#define RES 128           // grid resolution
#define NPT (RES * RES)   // 16384 points per (b,t)

// Two blocks per (b,t): grid = 2*BS*T = 2048 -> 8 blocks/CU (full occupancy).
// min/max of the Gaussian over the grid is computed ANALYTICALLY per block
// (convexity of the quadratic form), so the main loop streams compute->store
// with no value array and no block-wide data dependency.
__global__ __launch_bounds__(256) void AnalyticalDecoder_85581518340204_kernel(
    const float* __restrict__ mu,
    const float* __restrict__ covar,
    float* __restrict__ out)
{
    const int bid  = blockIdx.x;
    const int bt   = bid >> 1;    // 0..1023
    const int half = bid & 1;     // rows [0,64) or [64,128)
    const int tid  = threadIdx.x; // 0..255

    const float mux = mu[bt * 2 + 0];
    const float muy = mu[bt * 2 + 1];
    const float a = covar[bt * 4 + 0];
    const float b = covar[bt * 4 + 1];
    const float c = covar[bt * 4 + 2];
    const float d = covar[bt * 4 + 3];
    const float det = a * d - b * c;

    // s(dx,dy) = -0.5*log2(e)*q  so that prob = exp2(s). Normalization cancels
    // the 1/(2*pi*sqrt(det)) constant.
    const float LOG2E = 1.4426950408889634f;
    const float ninv2 = -0.5f * LOG2E / det;
    const float Kd  = ninv2 * d;        // * dx^2
    const float Kbc = -ninv2 * (b + c); // * dx*dy
    const float Ka  = ninv2 * a;        // * dy^2

    const float step    = 30.0f / 127.0f;
    const float invstep = 127.0f / 30.0f;

    // ---- analytic extrema over the 128x128 grid ----
    // max prob: q convex => per-row discrete min of q at floor/ceil of the
    // continuous minimizer dx* = (b+c)*dy/(2d), clamped; then min over rows.
    const int   r   = tid & 127;  // each row handled (redundantly x2)
    const float dyr = (-15.0f + (float)r * step) - muy;
    const float dxs = (b + c) * dyr / (2.0f * d);
    const float jc  = (mux + dxs + 15.0f) * invstep;
    int k0 = (int)floorf(jc);
    k0 = max(0, min(126, k0));
    const float dx0 = (-15.0f + (float)k0 * step) - mux;
    const float dx1 = dx0 + step;
    const float dyr2 = Ka * dyr * dyr;
    const float s0 = Kd * dx0 * dx0 + Kbc * dx0 * dyr + dyr2;
    const float s1 = Kd * dx1 * dx1 + Kbc * dx1 * dyr + dyr2;
    float smax = fmaxf(s0, s1);

    // min prob: max of q over grid is at one of the 4 corners (convexity).
    float smin = 3.4e38f;
    #pragma unroll
    for (int ci = 0; ci < 2; ++ci) {
        const float dyc = (ci ? 15.0f : -15.0f) - muy;
        #pragma unroll
        for (int cj = 0; cj < 2; ++cj) {
            const float dxc = (cj ? 15.0f : -15.0f) - mux;
            smin = fminf(smin, Kd * dxc * dxc + Kbc * dxc * dyc + Ka * dyc * dyc);
        }
    }

    // block max-reduce of smax (wave64 butterfly + 4-wave LDS combine)
    #pragma unroll
    for (int off = 32; off > 0; off >>= 1)
        smax = fmaxf(smax, __shfl_xor(smax, off));
    __shared__ float sm[4];
    const int wave = tid >> 6;
    if ((tid & 63) == 0) sm[wave] = smax;
    __syncthreads();
    smax = fmaxf(fmaxf(sm[0], sm[1]), fmaxf(sm[2], sm[3]));

    const float mxp = exp2f(smax);
    const float mnp = exp2f(smin);
    const float inv = 1.0f / (mxp - mnp);

    // ---- streaming compute + store: 32 points/thread (8 rows x 4 cols) ----
    const int j0 = (tid & 31) * 4;
    float C0[4], C1[4];
    #pragma unroll
    for (int e = 0; e < 4; ++e) {
        const float dx = (-15.0f + (float)(j0 + e) * step) - mux;
        C0[e] = Kd * dx * dx;
        C1[e] = Kbc * dx;
    }
    const int i0 = tid >> 5;
    float4* out4 = (float4*)(out + (size_t)bt * NPT + half * (NPT / 2));
    #pragma unroll
    for (int it = 0; it < 8; ++it) {
        const int   i  = half * 64 + it * 8 + i0;
        const float dy = (-15.0f + (float)i * step) - muy;
        const float t1 = Ka * dy;
        float4 v;
        v.x = (exp2f(C0[0] + dy * (C1[0] + t1)) - mnp) * inv;
        v.y = (exp2f(C0[1] + dy * (C1[1] + t1)) - mnp) * inv;
        v.z = (exp2f(C0[2] + dy * (C1[2] + t1)) - mnp) * inv;
        v.w = (exp2f(C0[3] + dy * (C1[3] + t1)) - mnp) * inv;
        out4[it * 256 + tid] = v;
    }
}

extern "C" void kernel_launch(void* const* d_in, const int* in_sizes, int n_in,
                              void* d_out, int out_size, void* d_ws, size_t ws_size,
                              hipStream_t stream) {
    const float* mu    = (const float*)d_in[0];   // [BS,T,2]
    const float* covar = (const float*)d_in[1];   // [BS,T,2,2]
    float* out = (float*)d_out;                   // [BS,T,1,RES,RES] f32
    const int n_bt = in_sizes[0] / 2;             // BS*T = 1024
    AnalyticalDecoder_85581518340204_kernel<<<n_bt * 2, 256, 0, stream>>>(mu, covar, out);
}

// Round 4
// 17.250 us; speedup vs baseline: 1.0133x; 1.0133x over previous
//
#include <hip/hip_runtime.h>

#define RES 128           // grid resolution
#define NPT (RES * RES)   // 16384 points per (b,t)

typedef float f32x4 __attribute__((ext_vector_type(4)));  // native vector: OK for nontemporal builtin

// Two blocks per (b,t). Analytic extrema (convexity of the quadratic form),
// streaming compute->store main loop, NONTEMPORAL stores so no dirty L2
// lines remain at kernel end (avoids the end-of-kernel writeback drain).
__global__ __launch_bounds__(256) void AnalyticalDecoder_85581518340204_kernel(
    const float* __restrict__ mu,
    const float* __restrict__ covar,
    float* __restrict__ out)
{
    const int bid  = blockIdx.x;
    const int bt   = bid >> 1;    // 0..1023
    const int half = bid & 1;     // rows [0,64) or [64,128)
    const int tid  = threadIdx.x; // 0..255

    const float mux = mu[bt * 2 + 0];
    const float muy = mu[bt * 2 + 1];
    const float a = covar[bt * 4 + 0];
    const float b = covar[bt * 4 + 1];
    const float c = covar[bt * 4 + 2];
    const float d = covar[bt * 4 + 3];
    const float det = a * d - b * c;

    // s(dx,dy) = -0.5*log2(e)*q  so that prob = exp2(s). Normalization cancels
    // the 1/(2*pi*sqrt(det)) constant.
    const float LOG2E = 1.4426950408889634f;
    const float ninv2 = -0.5f * LOG2E / det;
    const float Kd  = ninv2 * d;        // * dx^2
    const float Kbc = -ninv2 * (b + c); // * dx*dy
    const float Ka  = ninv2 * a;        // * dy^2

    const float step    = 30.0f / 127.0f;
    const float invstep = 127.0f / 30.0f;

    // ---- analytic extrema over the 128x128 grid ----
    // max prob: per-row discrete min of q at floor/ceil of the continuous
    // minimizer, clamped; then min over rows (q convex).
    const int   r   = tid & 127;
    const float dyr = (-15.0f + (float)r * step) - muy;
    const float dxs = (b + c) * dyr / (2.0f * d);
    const float jc  = (mux + dxs + 15.0f) * invstep;
    int k0 = (int)floorf(jc);
    k0 = max(0, min(126, k0));
    const float dx0 = (-15.0f + (float)k0 * step) - mux;
    const float dx1 = dx0 + step;
    const float dyr2 = Ka * dyr * dyr;
    const float s0 = Kd * dx0 * dx0 + Kbc * dx0 * dyr + dyr2;
    const float s1 = Kd * dx1 * dx1 + Kbc * dx1 * dyr + dyr2;
    float smax = fmaxf(s0, s1);

    // min prob: max of q over the grid is at one of the 4 corners.
    float smin = 3.4e38f;
    #pragma unroll
    for (int ci = 0; ci < 2; ++ci) {
        const float dyc = (ci ? 15.0f : -15.0f) - muy;
        #pragma unroll
        for (int cj = 0; cj < 2; ++cj) {
            const float dxc = (cj ? 15.0f : -15.0f) - mux;
            smin = fminf(smin, Kd * dxc * dxc + Kbc * dxc * dyc + Ka * dyc * dyc);
        }
    }

    // block max-reduce of smax
    #pragma unroll
    for (int off = 32; off > 0; off >>= 1)
        smax = fmaxf(smax, __shfl_xor(smax, off));
    __shared__ float sm[4];
    const int wave = tid >> 6;
    if ((tid & 63) == 0) sm[wave] = smax;
    __syncthreads();
    smax = fmaxf(fmaxf(sm[0], sm[1]), fmaxf(sm[2], sm[3]));

    const float mxp = exp2f(smax);
    const float mnp = exp2f(smin);
    const float inv = 1.0f / (mxp - mnp);
    const float mo  = mnp * inv;   // v = e*inv - mo  (one FMA per point)

    // ---- streaming compute + nontemporal store: 8 rows x 4 cols/thread ----
    const int j0 = (tid & 31) * 4;
    float C0[4], C1[4];
    #pragma unroll
    for (int e = 0; e < 4; ++e) {
        const float dx = (-15.0f + (float)(j0 + e) * step) - mux;
        C0[e] = Kd * dx * dx;
        C1[e] = Kbc * dx;
    }
    const int i0 = tid >> 5;
    f32x4* out4 = (f32x4*)(out + (size_t)bt * NPT + half * (NPT / 2));
    #pragma unroll
    for (int it = 0; it < 8; ++it) {
        const int   i  = half * 64 + it * 8 + i0;
        const float dy = (-15.0f + (float)i * step) - muy;
        const float t1 = Ka * dy;
        f32x4 v;
        v.x = fmaf(exp2f(C0[0] + dy * (C1[0] + t1)), inv, -mo);
        v.y = fmaf(exp2f(C0[1] + dy * (C1[1] + t1)), inv, -mo);
        v.z = fmaf(exp2f(C0[2] + dy * (C1[2] + t1)), inv, -mo);
        v.w = fmaf(exp2f(C0[3] + dy * (C1[3] + t1)), inv, -mo);
        __builtin_nontemporal_store(v, &out4[it * 256 + tid]);
    }
}

extern "C" void kernel_launch(void* const* d_in, const int* in_sizes, int n_in,
                              void* d_out, int out_size, void* d_ws, size_t ws_size,
                              hipStream_t stream) {
    const float* mu    = (const float*)d_in[0];   // [BS,T,2]
    const float* covar = (const float*)d_in[1];   // [BS,T,2,2]
    float* out = (float*)d_out;                   // [BS,T,1,RES,RES] f32
    const int n_bt = in_sizes[0] / 2;             // BS*T = 1024
    AnalyticalDecoder_85581518340204_kernel<<<n_bt * 2, 256, 0, stream>>>(mu, covar, out);
}